// Round 16
// baseline (29.467 us; speedup 1.0000x reference)
//
#include <hip/hip_runtime.h>
#include <hip/hip_bf16.h>
#include <math.h>

#define NB 32
#define NL 128
#define ND 128

typedef __attribute__((ext_vector_type(8))) short bf16x8;
typedef __attribute__((ext_vector_type(4))) float f32x4;

union F4  { float4 v; float f[4]; };
union BF8 { bf16x8 v; ushort u[8]; };

__device__ inline ushort f2bf(float f) {
    __hip_bfloat16 h = __float2bfloat16(f);
    union { __hip_bfloat16 h; ushort u; } c; c.h = h; return c.u;
}
__device__ inline float bf2f(ushort u) {
    union { unsigned int i; float f; } c; c.i = ((unsigned int)u) << 16; return c.f;
}
__device__ inline short2 bsplit(float f) {
    ushort hu = f2bf(f);
    short2 r;
    r.x = (short)hu;
    r.y = (short)f2bf(f - bf2f(hu));
    return r;
}

// ---------------------------------------------------------------------------
// k_one: ONE data-parallel kernel, grid 256 = b(32) x {term,dq,eo}(8),
// block 512 = 8 waves. Zero cross-block deps. r15 with the proj MFMA
// orientation SWAPPED: A = W (stationary, d-rows), B = X (streamed from
// LDS, l-cols) -> C[d][l] — the same orientation the verified gram uses,
// and exactly G's layout. Phases pair mats sharing one X array
// ({Wr1,Wr2}<-xr then {Wi1,Wi2}<-xi): each X fragment read feeds
// 2 mats x 3 split-MFMA = 6 MFMA -> LDS reads halved vs r15 (128/wave).
//
// Proj: wave w owns d-tile w. W frags: 16 global loads/wave/phase
//   (L2-hot) + in-reg bsplit. X staged fp32->bf16 hi/lo per phase
//   (single 64K buffer, reused across phases). Split MFMA: WhXh+WhXl+WlXh.
// Epilogue: bias; logit partials (2 shfls: lane holds 4 d of one l);
//   y2/y3 -> G as scalar ushort stores (r8-verified swizzled [d][l]);
//   cross-wave logit reduce via lgp[2][8][128].
// Softmax: block's term, waves 0-1 (r11-verified).
// Gram: r15 verbatim (G resident; in-register A-scale).
// LDS: G 64K @0, Xbuf 64K @65536, lgp 8K @131072, wfl/wred after (~137K).
// ---------------------------------------------------------------------------
__global__ __launch_bounds__(512, 1) void k_one(
    const float* __restrict__ xr, const float* __restrict__ xi,
    const float* __restrict__ Wr1, const float* __restrict__ br1,
    const float* __restrict__ Wi1, const float* __restrict__ bi1,
    const float* __restrict__ Wr2, const float* __restrict__ br2,
    const float* __restrict__ Wi2, const float* __restrict__ bi2,
    float* __restrict__ out)
{
    extern __shared__ char L[];
    char*  Gr2 = L;                      // 32768: bf16 G[d][l] (r2), swizzled
    char*  Gi2 = L + 32768;              // 32768: bf16 G[d][l] (i2)
    char*  Xh  = L + 65536;              // 32768: bf16 X hi [l][k], swizzled
    char*  Xl  = L + 98304;              // 32768: bf16 X lo
    float* lgp = (float*)(L + 131072);   // [2 c][8 w][128 l]
    float* wfl = (float*)(L + 139264);   // [128]
    float* wred= (float*)(L + 139776);   // 4 floats

    const int t     = threadIdx.x;
    const int w     = t >> 6;            // 0..7 = d-tile
    const int lane  = t & 63;
    const int l15   = lane & 15;
    const int koff8 = (lane >> 4) * 8;
    const int koffb = koff8 * 2;

    const int bid  = blockIdx.x;
    const int b    = bid >> 3;
    const int sub  = bid & 7;
    const int term = sub >> 2;
    const int dq   = (sub >> 1) & 1;
    const int eo   = sub & 1;

    const int drow = w * 16 + l15;       // A-side (W) row = d

#define STAGEX(XP)                                                            \
    {                                                                         \
        const int row_ = t >> 2;                                              \
        const int s0_  = (t & 3) * 4;                                         \
        const float* p_ = (XP) + (size_t)(b * NL + row_) * ND;                \
        const int sw_ = (row_ & 7) << 4;                                      \
        _Pragma("unroll")                                                     \
        for (int j = 0; j < 4; ++j) {                                         \
            const int slot_ = s0_ + j;                                        \
            F4 f0_, f1_;                                                      \
            f0_.v = *(const float4*)&p_[slot_ * 8];                           \
            f1_.v = *(const float4*)&p_[slot_ * 8 + 4];                       \
            bf16x8 h_, l_;                                                    \
            _Pragma("unroll")                                                 \
            for (int e = 0; e < 4; ++e) {                                     \
                short2 sa = bsplit(f0_.f[e]); h_[e] = sa.x; l_[e] = sa.y;     \
                short2 sb = bsplit(f1_.f[e]); h_[4 + e] = sb.x; l_[4 + e] = sb.y; \
            }                                                                 \
            const int byte_ = row_ * 256 + ((slot_ * 16) ^ sw_);              \
            *(bf16x8*)(Xh + byte_) = h_;                                      \
            *(bf16x8*)(Xl + byte_) = l_;                                      \
        }                                                                     \
    }

#define LOADWF(W0, W2)                                                        \
    {                                                                         \
        const float* Wps[2] = {W0, W2};                                       \
        _Pragma("unroll")                                                     \
        for (int mi = 0; mi < 2; ++mi) {                                      \
            const float* wr_ = Wps[mi] + (size_t)drow * ND;                   \
            _Pragma("unroll")                                                 \
            for (int ks = 0; ks < 4; ++ks) {                                  \
                F4 f0_, f1_;                                                  \
                f0_.v = *(const float4*)&wr_[ks * 32 + koff8];                \
                f1_.v = *(const float4*)&wr_[ks * 32 + koff8 + 4];            \
                bf16x8 h_, l_;                                                \
                _Pragma("unroll")                                             \
                for (int e = 0; e < 4; ++e) {                                 \
                    short2 sa = bsplit(f0_.f[e]); h_[e] = sa.x; l_[e] = sa.y; \
                    short2 sb = bsplit(f1_.f[e]); h_[4 + e] = sb.x; l_[4 + e] = sb.y; \
                }                                                             \
                awh[mi][ks] = h_;                                             \
                awl[mi][ks] = l_;                                             \
            }                                                                 \
        }                                                                     \
    }

#define PHASE(ACC)                                                            \
    {                                                                         \
        const int xsw = (l15 & 7) << 4;                                       \
        _Pragma("unroll")                                                     \
        for (int lt = 0; lt < 8; ++lt) {                                      \
            const int xbase = (lt * 16 + l15) * 256;                          \
            _Pragma("unroll")                                                 \
            for (int ks = 0; ks < 4; ++ks) {                                  \
                const int off = xbase + (((ks * 64) + koffb) ^ xsw);          \
                bf16x8 bh = *(const bf16x8*)(Xh + off);                       \
                bf16x8 bl = *(const bf16x8*)(Xl + off);                       \
                _Pragma("unroll")                                             \
                for (int mi = 0; mi < 2; ++mi) {                              \
                    ACC[mi][lt] = __builtin_amdgcn_mfma_f32_16x16x32_bf16(awh[mi][ks], bh, ACC[mi][lt], 0, 0, 0); \
                    ACC[mi][lt] = __builtin_amdgcn_mfma_f32_16x16x32_bf16(awh[mi][ks], bl, ACC[mi][lt], 0, 0, 0); \
                    ACC[mi][lt] = __builtin_amdgcn_mfma_f32_16x16x32_bf16(awl[mi][ks], bh, ACC[mi][lt], 0, 0, 0); \
                }                                                             \
            }                                                                 \
        }                                                                     \
    }

    f32x4 accP0[2][8], accP1[2][8];   // [mi][l-tile]: phase0 = {r1, r2}, phase1 = {i1, i2}
#pragma unroll
    for (int mi = 0; mi < 2; ++mi)
#pragma unroll
        for (int lt = 0; lt < 8; ++lt) {
            accP0[mi][lt] = (f32x4){0.f, 0.f, 0.f, 0.f};
            accP1[mi][lt] = (f32x4){0.f, 0.f, 0.f, 0.f};
        }

    bf16x8 awh[2][4], awl[2][4];

    // ---- phase 0: X = xr, mats {Wr1, Wr2} ----
    STAGEX(xr)
    LOADWF(Wr1, Wr2)
    __syncthreads();
    PHASE(accP0)
    __syncthreads();          // X-buf reads done before restage

    // ---- phase 1: X = xi, mats {Wi1, Wi2} ----
    STAGEX(xi)
    LOADWF(Wi1, Wi2)
    __syncthreads();
    PHASE(accP1)

    // ---- epilogue: bias, logit partials, G scalar stores ----
    const int dbq = w * 16 + (lane >> 4) * 4;
    F4 bv0, bv1, bv2, bv3;
    bv0.v = *(const float4*)&br1[dbq];
    bv1.v = *(const float4*)&bi1[dbq];
    bv2.v = *(const float4*)&br2[dbq];
    bv3.v = *(const float4*)&bi2[dbq];

    float pRl[8], pIl[8];
#pragma unroll
    for (int lt = 0; lt < 8; ++lt) {
        const int l = lt * 16 + l15;
        float sR = 0.f, sI = 0.f;
#pragma unroll
        for (int r = 0; r < 4; ++r) {
            float y0 = accP0[0][lt][r] + bv0.f[r];   // r1
            float y1 = accP1[0][lt][r] + bv1.f[r];   // i1
            float y2 = accP0[1][lt][r] + bv2.f[r];   // r2
            float y3 = accP1[1][lt][r] + bv3.f[r];   // i2
            sR += (y0 * y0 - y1 * y1) * (y2 * y2 - y3 * y3);
            sI += 4.f * y0 * y1 * y2 * y3;
            const int d = dbq + r;
            const int byte = d * 256 + ((2 * l) ^ ((d & 7) << 4));
            *(ushort*)(Gr2 + byte) = f2bf(y2);
            *(ushort*)(Gi2 + byte) = f2bf(y3);
        }
        sR += __shfl_xor(sR, 16); sR += __shfl_xor(sR, 32);
        sI += __shfl_xor(sI, 16); sI += __shfl_xor(sI, 32);
        pRl[lt] = sR; pIl[lt] = sI;
    }
    if (lane < 16) {
#pragma unroll
        for (int lt = 0; lt < 8; ++lt) {
            lgp[(0 * 8 + w) * 128 + lt * 16 + l15] = pRl[lt];
            lgp[(1 * 8 + w) * 128 + lt * 16 + l15] = pIl[lt];
        }
    }
    __syncthreads();   // G + lgp visible block-wide

    // ---- softmax for this block's term (threads 0-127) ----
    float sv = 0.f, se = 0.f;
    if (t < 128) {
#pragma unroll
        for (int w8 = 0; w8 < 8; ++w8)
            sv += lgp[(term * 8 + w8) * 128 + t];
        float m = sv;
#pragma unroll
        for (int off = 1; off < 64; off <<= 1) m = fmaxf(m, __shfl_xor(m, off));
        if (lane == 0) wred[w] = m;
    }
    __syncthreads();
    if (t < 128) {
        float m = fmaxf(wred[0], wred[1]);
        se = expf(sv - m);
        float s = se;
#pragma unroll
        for (int off = 1; off < 64; off <<= 1) s += __shfl_xor(s, off);
        if (lane == 0) wred[2 + w] = s;
    }
    __syncthreads();
    if (t < 128) wfl[t] = se / (wred[2] + wred[3]);
    __syncthreads();

    // ---- gram MFMA: wave w -> m-tile w&3, nt-pair w>>2 (r15-verified) ----
    const int mt  = w & 3;
    const int ntp = w >> 2;

    f32x4 accP[2], accN[2];
#pragma unroll
    for (int n = 0; n < 2; ++n) {
        accP[n] = (f32x4){0.f, 0.f, 0.f, 0.f};
        accN[n] = (f32x4){0.f, 0.f, 0.f, 0.f};
    }

#pragma unroll
    for (int ks = 0; ks < 4; ++ks) {
        F4 w0, w1;
        w0.v = *(const float4*)&wfl[ks * 32 + koff8];
        w1.v = *(const float4*)&wfl[ks * 32 + koff8 + 4];
        float wv[8] = {w0.f[0], w0.f[1], w0.f[2], w0.f[3],
                       w1.f[0], w1.f[1], w1.f[2], w1.f[3]};

        const int ar = dq * 64 + mt * 16 + l15;
        const int ab = ar * 256 + (((ks * 64) + koffb) ^ ((ar & 7) << 4));
        BF8 a0; a0.v = *(const bf16x8*)(Gr2 + ab);
        BF8 a1; a1.v = *(const bf16x8*)(Gi2 + ab);
        bf16x8 s0, s1;
#pragma unroll
        for (int e = 0; e < 8; ++e) {
            s0[e] = (short)f2bf(bf2f(a0.u[e]) * wv[e]);
            s1[e] = (short)f2bf(bf2f(a1.u[e]) * wv[e]);
        }
        bf16x8 aP = term ? s1 : s0;   // R: wr.r2 ; I: wi.i2
        bf16x8 aN = term ? s0 : s1;   // R: wr.i2 ; I: wi.r2

#pragma unroll
        for (int n = 0; n < 2; ++n) {
            const int br = eo * 64 + (ntp * 2 + n) * 16 + l15;
            const int bb = br * 256 + (((ks * 64) + koffb) ^ ((br & 7) << 4));
            bf16x8 b0 = *(const bf16x8*)(Gr2 + bb);
            bf16x8 b1 = *(const bf16x8*)(Gi2 + bb);
            accP[n] = __builtin_amdgcn_mfma_f32_16x16x32_bf16(aP, b0, accP[n], 0, 0, 0);
            accN[n] = __builtin_amdgcn_mfma_f32_16x16x32_bf16(aN, b1, accN[n], 0, 0, 0);
        }
    }

    const float sgn = term ? 1.f : -1.f;
    float* dst = out + (size_t)term * NB * ND * ND + (size_t)b * ND * ND;
    const int rb = dq * 64 + mt * 16 + (lane >> 4) * 4;
#pragma unroll
    for (int n = 0; n < 2; ++n) {
        const int ec = eo * 64 + (ntp * 2 + n) * 16 + l15;
#pragma unroll
        for (int r = 0; r < 4; ++r)
            dst[(size_t)(rb + r) * ND + ec] = accP[n][r] + sgn * accN[n][r];
    }
}

extern "C" void kernel_launch(void* const* d_in, const int* in_sizes, int n_in,
                              void* d_out, int out_size, void* d_ws, size_t ws_size,
                              hipStream_t stream)
{
    const float* xr  = (const float*)d_in[0];
    const float* xi  = (const float*)d_in[1];
    const float* Wr1 = (const float*)d_in[2];
    const float* br1 = (const float*)d_in[3];
    const float* Wi1 = (const float*)d_in[4];
    const float* bi1 = (const float*)d_in[5];
    const float* Wr2 = (const float*)d_in[6];
    const float* br2 = (const float*)d_in[7];
    const float* Wi2 = (const float*)d_in[8];
    const float* bi2 = (const float*)d_in[9];

    (void)hipFuncSetAttribute((const void*)k_one,
                              hipFuncAttributeMaxDynamicSharedMemorySize, 139840);

    hipLaunchKernelGGL(k_one, dim3(256), dim3(512), 139840, stream,
                       xr, xi, Wr1, br1, Wi1, bi1, Wr2, br2, Wi2, bi2,
                       (float*)d_out);
}

// Round 17
// 25.250 us; speedup vs baseline: 1.1670x; 1.1670x over previous
//
#include <hip/hip_runtime.h>
#include <hip/hip_bf16.h>
#include <math.h>

#define NB 32
#define NL 128
#define ND 128

typedef __attribute__((ext_vector_type(8))) short bf16x8;
typedef __attribute__((ext_vector_type(4))) float f32x4;

union F4  { float4 v; float f[4]; };
union BF8 { bf16x8 v; ushort u[8]; };

__device__ inline ushort f2bf(float f) {
    __hip_bfloat16 h = __float2bfloat16(f);
    union { __hip_bfloat16 h; ushort u; } c; c.h = h; return c.u;
}
__device__ inline float bf2f(ushort u) {
    union { unsigned int i; float f; } c; c.i = ((unsigned int)u) << 16; return c.f;
}
__device__ inline short2 bsplit(float f) {
    ushort hu = f2bf(f);
    short2 r;
    r.x = (short)hu;
    r.y = (short)f2bf(f - bf2f(hu));
    return r;
}

// ---------------------------------------------------------------------------
// k_proj: grid 256 = b(32) x l-tile(8 of 16 rows). Block 256 (4 waves).
// Wave w covers n-tiles {2w, 2w+1} (32 d). acc[4 mats][2] = 32 VGPR.
// A = X fp32 from global + in-reg bsplit (HW-verified ABt fragment pattern).
// B = W fp32 from global (L2-hot, block-uniform) + in-reg bsplit.
// Split-bf16 MFMA: XhWh + XhWl + XlWh (r6-verified).
// Epilogue: bias; logits (16-lane shfl + cross-wave LDS reduce) -> lgG;
// y2/y3 bf16 -> gtb[arr][b][d][l].
// [r16 post-mortem: this 2-node structure is the measured optimum; the
//  binding constraint is ~9.5us/graph-node launch overhead, not kernel
//  cycles. Single-node variants require 8x proj redundancy (body >=16us)
//  and lose; cross-block sync costs ~100us on MI355X (r10/r12).]
// ---------------------------------------------------------------------------
__global__ __launch_bounds__(256) void k_proj(
    const float* __restrict__ xr, const float* __restrict__ xi,
    const float* __restrict__ Wr1, const float* __restrict__ br1,
    const float* __restrict__ Wi1, const float* __restrict__ bi1,
    const float* __restrict__ Wr2, const float* __restrict__ br2,
    const float* __restrict__ Wi2, const float* __restrict__ bi2,
    ushort* __restrict__ gtb, float* __restrict__ lgG)
{
    __shared__ float lgpart[2 * 4 * 16];   // [c][wave][row]

    const int bid   = blockIdx.x;
    const int t     = threadIdx.x;
    const int w     = t >> 6;
    const int lane  = t & 63;
    const int l15   = lane & 15;
    const int koff8 = (lane >> 4) * 8;
    const int b     = bid >> 3;
    const int lt    = bid & 7;
    const int arowg = b * NL + lt * 16 + l15;

    // ---- A-fragments: X fp32 -> in-reg split ----
    bf16x8 axh[2][4], axl[2][4];
    {
        const float* xs[2] = {xr, xi};
#pragma unroll
        for (int arr = 0; arr < 2; ++arr)
#pragma unroll
            for (int ks = 0; ks < 4; ++ks) {
                const float* p = xs[arr] + (size_t)arowg * ND + ks * 32 + koff8;
                F4 f0, f1;
                f0.v = *(const float4*)&p[0];
                f1.v = *(const float4*)&p[4];
                bf16x8 h, l;
#pragma unroll
                for (int e = 0; e < 4; ++e) {
                    short2 s = bsplit(f0.f[e]); h[e] = s.x; l[e] = s.y;
                }
#pragma unroll
                for (int e = 0; e < 4; ++e) {
                    short2 s = bsplit(f1.f[e]); h[4 + e] = s.x; l[4 + e] = s.y;
                }
                axh[arr][ks] = h;
                axl[arr][ks] = l;
            }
    }

    // ---- proj MFMA: B-frags straight from W fp32 (L2) + in-reg split ----
    f32x4 acc[4][2];
#pragma unroll
    for (int m = 0; m < 4; ++m)
#pragma unroll
        for (int n = 0; n < 2; ++n) acc[m][n] = (f32x4){0.f, 0.f, 0.f, 0.f};

    {
        const float* Ws[4] = {Wr1, Wi1, Wr2, Wi2};
#pragma unroll
        for (int mat = 0; mat < 4; ++mat) {
            const int arr = mat & 1;
#pragma unroll
            for (int n = 0; n < 2; ++n) {
                const float* wrow = Ws[mat] + (size_t)((w * 2 + n) * 16 + l15) * ND;
#pragma unroll
                for (int ks = 0; ks < 4; ++ks) {
                    F4 f0, f1;
                    f0.v = *(const float4*)&wrow[ks * 32 + koff8];
                    f1.v = *(const float4*)&wrow[ks * 32 + koff8 + 4];
                    bf16x8 bh, bl;
#pragma unroll
                    for (int e = 0; e < 4; ++e) {
                        short2 s = bsplit(f0.f[e]); bh[e] = s.x; bl[e] = s.y;
                    }
#pragma unroll
                    for (int e = 0; e < 4; ++e) {
                        short2 s = bsplit(f1.f[e]); bh[4 + e] = s.x; bl[4 + e] = s.y;
                    }
                    acc[mat][n] = __builtin_amdgcn_mfma_f32_16x16x32_bf16(axh[arr][ks], bh, acc[mat][n], 0, 0, 0);
                    acc[mat][n] = __builtin_amdgcn_mfma_f32_16x16x32_bf16(axh[arr][ks], bl, acc[mat][n], 0, 0, 0);
                    acc[mat][n] = __builtin_amdgcn_mfma_f32_16x16x32_bf16(axl[arr][ks], bh, acc[mat][n], 0, 0, 0);
                }
            }
        }
    }

    // ---- epilogue: bias, partial logits, G writes ----
    float pR[4] = {0.f, 0.f, 0.f, 0.f};
    float pI[4] = {0.f, 0.f, 0.f, 0.f};
    const int lbase = lt * 16 + (lane >> 4) * 4;
#pragma unroll
    for (int n = 0; n < 2; ++n) {
        const int d = (w * 2 + n) * 16 + l15;
        const float b0 = br1[d], b1 = bi1[d], b2 = br2[d], b3 = bi2[d];
        ushort g2[4], g3[4];
#pragma unroll
        for (int r = 0; r < 4; ++r) {
            float y0 = acc[0][n][r] + b0;
            float y1 = acc[1][n][r] + b1;
            float y2 = acc[2][n][r] + b2;
            float y3 = acc[3][n][r] + b3;
            pR[r] += (y0 * y0 - y1 * y1) * (y2 * y2 - y3 * y3);
            pI[r] += 4.f * y0 * y1 * y2 * y3;
            g2[r] = f2bf(y2);
            g3[r] = f2bf(y3);
        }
        ushort4 q2 = {g2[0], g2[1], g2[2], g2[3]};
        ushort4 q3 = {g3[0], g3[1], g3[2], g3[3]};
        *(ushort4*)&gtb[((size_t)(0 * NB + b) * ND + d) * NL + lbase] = q2;
        *(ushort4*)&gtb[((size_t)(1 * NB + b) * ND + d) * NL + lbase] = q3;
    }

#pragma unroll
    for (int off = 1; off < 16; off <<= 1)
#pragma unroll
        for (int r = 0; r < 4; ++r) {
            pR[r] += __shfl_xor(pR[r], off);
            pI[r] += __shfl_xor(pI[r], off);
        }
    if (l15 == 0) {
        const int row = (lane >> 4) * 4;
#pragma unroll
        for (int r = 0; r < 4; ++r) {
            lgpart[(0 * 4 + w) * 16 + row + r] = pR[r];
            lgpart[(1 * 4 + w) * 16 + row + r] = pI[r];
        }
    }
    __syncthreads();
    if (t < 32) {
        const int c = t >> 4, row = t & 15;
        float s = lgpart[(c * 4 + 0) * 16 + row] + lgpart[(c * 4 + 1) * 16 + row]
                + lgpart[(c * 4 + 2) * 16 + row] + lgpart[(c * 4 + 3) * 16 + row];
        lgG[(size_t)(c * NB + b) * NL + lt * 16 + row] = s;
    }
}

// ---------------------------------------------------------------------------
// k_gram: grid 256 = b(32) x {term, dq, eo}(8). Block 256 (4 waves).
// Wave-parallel softmax (redundant per block) -> wfl; stage G (64 KB LDS,
// XOR-swizzled); gram MFMA with in-register A-scale:
//   Mr = (wr.r2)r2^T - (wr.i2)i2^T ; Mi = (wi.i2)r2^T + (wi.r2)i2^T.
// ---------------------------------------------------------------------------
__global__ __launch_bounds__(256) void k_gram(
    const ushort* __restrict__ gtb, const float* __restrict__ lgG,
    float* __restrict__ out)
{
    extern __shared__ char L[];
    float* wfl  = (float*)(L + 65536);
    float* wred = (float*)(L + 66048);

    const int bid   = blockIdx.x;
    const int t     = threadIdx.x;
    const int w     = t >> 6;
    const int lane  = t & 63;
    const int l15   = lane & 15;
    const int koff8 = (lane >> 4) * 8;
    const int koffb = koff8 * 2;

    const int b    = bid >> 3;
    const int sub  = bid & 7;
    const int term = sub >> 2;
    const int dq   = (sub >> 1) & 1;
    const int eo   = sub & 1;

    // ---- softmax (waves 0,1) ----
    float sv = 0.f, se = 0.f;
    if (t < 128) {
        sv = lgG[(size_t)(term * NB + b) * NL + t];
        float m = sv;
#pragma unroll
        for (int off = 1; off < 64; off <<= 1) m = fmaxf(m, __shfl_xor(m, off));
        if (lane == 0) wred[w] = m;
    }
    __syncthreads();
    if (t < 128) {
        float m = fmaxf(wred[0], wred[1]);
        se = expf(sv - m);
        float s = se;
#pragma unroll
        for (int off = 1; off < 64; off <<= 1) s += __shfl_xor(s, off);
        if (lane == 0) wred[2 + w] = s;
    }
    __syncthreads();
    if (t < 128) wfl[t] = se / (wred[2] + wred[3]);

    // ---- stage G of batch b (both arrays), swizzled ----
#pragma unroll
    for (int j = 0; j < 16; ++j) {
        int u    = t + 256 * j;
        int arr  = u >> 11;
        int row  = (u >> 4) & 127;
        int slot = u & 15;
        bf16x8 v = *(const bf16x8*)&gtb[((size_t)(arr * NB + b) * ND + row) * NL + slot * 8];
        *(bf16x8*)(L + arr * 32768 + row * 256 + ((slot * 16) ^ ((row & 7) << 4))) = v;
    }
    __syncthreads();   // covers staging AND wfl writes

    // ---- gram MFMA ----
    f32x4 accP[4], accN[4];
#pragma unroll
    for (int nt = 0; nt < 4; ++nt) {
        accP[nt] = (f32x4){0.f, 0.f, 0.f, 0.f};
        accN[nt] = (f32x4){0.f, 0.f, 0.f, 0.f};
    }

#pragma unroll
    for (int ks = 0; ks < 4; ++ks) {
        F4 w0, w1;
        w0.v = *(const float4*)&wfl[ks * 32 + koff8];
        w1.v = *(const float4*)&wfl[ks * 32 + koff8 + 4];
        float wv[8] = {w0.f[0], w0.f[1], w0.f[2], w0.f[3],
                       w1.f[0], w1.f[1], w1.f[2], w1.f[3]};

        const int ar = dq * 64 + w * 16 + l15;
        const int ab = ar * 256 + (((ks * 64) + koffb) ^ ((ar & 7) << 4));
        BF8 a0; a0.v = *(const bf16x8*)(L + ab);
        BF8 a1; a1.v = *(const bf16x8*)(L + 32768 + ab);
        bf16x8 s0, s1;
#pragma unroll
        for (int e = 0; e < 8; ++e) {
            s0[e] = (short)f2bf(bf2f(a0.u[e]) * wv[e]);
            s1[e] = (short)f2bf(bf2f(a1.u[e]) * wv[e]);
        }
        bf16x8 aP = term ? s1 : s0;   // R: wr.r2 ; I: wi.i2
        bf16x8 aN = term ? s0 : s1;   // R: wr.i2 ; I: wi.r2

#pragma unroll
        for (int nt = 0; nt < 4; ++nt) {
            const int br = eo * 64 + nt * 16 + l15;
            const int bb = br * 256 + (((ks * 64) + koffb) ^ ((br & 7) << 4));
            bf16x8 b0 = *(const bf16x8*)(L + bb);
            bf16x8 b1 = *(const bf16x8*)(L + 32768 + bb);
            accP[nt] = __builtin_amdgcn_mfma_f32_16x16x32_bf16(aP, b0, accP[nt], 0, 0, 0);
            accN[nt] = __builtin_amdgcn_mfma_f32_16x16x32_bf16(aN, b1, accN[nt], 0, 0, 0);
        }
    }

    const float sgn = term ? 1.f : -1.f;
    float* dst = out + (size_t)term * NB * ND * ND + (size_t)b * ND * ND;
    const int rb = dq * 64 + w * 16 + (lane >> 4) * 4;
#pragma unroll
    for (int nt = 0; nt < 4; ++nt) {
        const int ec = eo * 64 + nt * 16 + l15;
#pragma unroll
        for (int r = 0; r < 4; ++r)
            dst[(size_t)(rb + r) * ND + ec] = accP[nt][r] + sgn * accN[nt][r];
    }
}

extern "C" void kernel_launch(void* const* d_in, const int* in_sizes, int n_in,
                              void* d_out, int out_size, void* d_ws, size_t ws_size,
                              hipStream_t stream)
{
    const float* xr  = (const float*)d_in[0];
    const float* xi  = (const float*)d_in[1];
    const float* Wr1 = (const float*)d_in[2];
    const float* br1 = (const float*)d_in[3];
    const float* Wi1 = (const float*)d_in[4];
    const float* bi1 = (const float*)d_in[5];
    const float* Wr2 = (const float*)d_in[6];
    const float* br2 = (const float*)d_in[7];
    const float* Wi2 = (const float*)d_in[8];
    const float* bi2 = (const float*)d_in[9];

    ushort* gtb = (ushort*)d_ws;                     // [2][b][d][l] bf16
    float*  lgG = (float*)(gtb + 2 * NB * ND * NL);  // [2][b][l]

    (void)hipFuncSetAttribute((const void*)k_gram,
                              hipFuncAttributeMaxDynamicSharedMemorySize, 66560);

    hipLaunchKernelGGL(k_proj, dim3(256), dim3(256), 0, stream,
                       xr, xi, Wr1, br1, Wi1, bi1, Wr2, br2, Wi2, bi2,
                       gtb, lgG);
    hipLaunchKernelGGL(k_gram, dim3(256), dim3(256), 66560, stream,
                       gtb, lgG, (float*)d_out);
}